// Round 18
// baseline (273.340 us; speedup 1.0000x reference)
//
#include <hip/hip_runtime.h>
#include <math.h>

typedef __bf16 bf16x8 __attribute__((ext_vector_type(8)));
typedef __bf16 bf16x4 __attribute__((ext_vector_type(4)));
typedef __bf16 bf16x2 __attribute__((ext_vector_type(2)));
typedef float f32x4 __attribute__((ext_vector_type(4)));

namespace {
constexpr int kD = 128;
constexpr float kEps = 1e-6f;
constexpr float kScale = 0.17677669529663687f;  // 1/sqrt(32)
constexpr float kNeg = -1000000000.0f;
constexpr float kLog2e = 1.4426950408889634f;
constexpr size_t kSZ = (size_t)128 * 256 * 128;  // 4,194,304
}

// ---------------------------------------------------------------------------
// Shared-memory pool (154.25 KB). e[127][128] f32 (tree scratch) aliases Xs.
// ---------------------------------------------------------------------------
struct SMem {
    __bf16 Xs[256 * 128];   // 64KB swizzled x (residual); tree e aliases this
    __bf16 Kls[256 * 32];   // 16KB XOR-swizzled K
    __bf16 Vt[32][276];     // 17.25KB V^T
    __bf16 Pl[8][1024];     // 16KB per-wave quarter-P
    __bf16 Qs[8][512];      // 8KB per-wave Q_h
    __bf16 Ctx[128 * 128];  // 32KB swizzled ctx
    float mb[256];          // mask bias (persists across phases)
};

__device__ __forceinline__ void glds16(const void* g, void* l) {
    __builtin_amdgcn_global_load_lds(
        (const __attribute__((address_space(1))) unsigned int*)g,
        (__attribute__((address_space(3))) unsigned int*)l, 16, 0, 0);
}

// Grid barrier: all 256 blocks co-resident (1 block/CU at 154KB LDS).
// cnt[i] zeroed per launch via hipMemsetAsync. Release fence + device-scope
// add; acquire spin; fence again before consuming other blocks' data.
__device__ __forceinline__ void gridbar(int* cnt, int nblk) {
    __syncthreads();
    if (threadIdx.x == 0) {
        __threadfence();
        atomicAdd(cnt, 1);
        while (__hip_atomic_load(cnt, __ATOMIC_ACQUIRE,
                                 __HIP_MEMORY_SCOPE_AGENT) < nblk)
            __builtin_amdgcn_s_sleep(2);
        __threadfence();
    }
    __syncthreads();
}

// ---------------------------------------------------------------------------
// Mega phase: QKV produce (pipelined) + attention + oproj + resid + LN1.
// LEAF2: strip-1 blocks also compute LN2(2*o1) for their rows (the tree
// leaves 128..255) straight from registers: 1 -> xb (pre-swizzled bf16),
// 2 -> xo2 (f32). STAGE: stage Xs from pre-swizzled xsrc via async DMA.
// ---------------------------------------------------------------------------
template <int WEIGHTS, bool STAGE, int LEAF2>
__device__ void mega_phase(
    SMem& sm, const void* xsrc, const __bf16* Wp,
    const float* bq, const float* bk, const float* bv, const float* bo,
    const float* g1, const float* b1, const float* g2, const float* b2,
    __bf16* O1, float* wout, float* l1out, float* xo2, __bf16* xb2)
{
    const int t = threadIdx.x;
    const int w = t >> 6, l = t & 63, lo = l & 15, g = l >> 4;
    const int b = blockIdx.x & 127, strip = blockIdx.x >> 7;
    const int q0 = strip * 128 + w * 16;
    const int tk0 = w * 32;
    const int kswz = (lo ^ (lo >> 2)) & 3;

    const __bf16* Wqp = Wp;
    const __bf16* Wkp = Wp + 16384;
    const __bf16* Wvp = Wp + 2 * 16384;
    const __bf16* Wop = Wp + 3 * 16384;

    if constexpr (STAGE) {
#pragma unroll
        for (int it = 0; it < 8; ++it)
            glds16((const __bf16*)xsrc + (size_t)b * 32768 + (it * 8 + w) * 512 + l * 8,
                   &sm.Xs[(it * 8 + w) * 512]);
        __syncthreads();
    }
    if (WEIGHTS && blockIdx.x == 0 && t == 0) l1out[0] = 1024.0f;

    auto wfrag = [&](const __bf16* W, int ni, int ks) {
        return *(const bf16x8*)(W + (((ni * 4 + ks) * 64 + l) << 3));
    };
    auto xfrag = [&](int row, int ks) {
        return *(const bf16x8*)&sm.Xs[row * 128 + (((g + 4 * ks) ^ (row & 7)) << 3)];
    };

    // head-invariant X fragments
    bf16x8 xa[2][4], xq[4];
#pragma unroll
    for (int ks = 0; ks < 4; ++ks) {
        xa[0][ks] = xfrag(tk0 + lo, ks);
        xa[1][ks] = xfrag(tk0 + 16 + lo, ks);
        xq[ks] = xfrag(q0 + lo, ks);
    }

    f32x4 kacc[2][2], vacc[2][2], qacc[2];

    auto produce_compute = [&](int h) {
#pragma unroll
        for (int i = 0; i < 2; ++i)
#pragma unroll
            for (int j2 = 0; j2 < 2; ++j2) {
                kacc[i][j2] = f32x4{0.f, 0.f, 0.f, 0.f};
                vacc[i][j2] = f32x4{0.f, 0.f, 0.f, 0.f};
            }
        qacc[0] = f32x4{0.f, 0.f, 0.f, 0.f};
        qacc[1] = f32x4{0.f, 0.f, 0.f, 0.f};
#pragma unroll
        for (int ks = 0; ks < 4; ++ks) {
            const bf16x8 wk0 = wfrag(Wkp, 2 * h, ks);
            const bf16x8 wk1 = wfrag(Wkp, 2 * h + 1, ks);
            const bf16x8 wv0 = wfrag(Wvp, 2 * h, ks);
            const bf16x8 wv1 = wfrag(Wvp, 2 * h + 1, ks);
            kacc[0][0] = __builtin_amdgcn_mfma_f32_16x16x32_bf16(wk0, xa[0][ks], kacc[0][0], 0, 0, 0);
            kacc[0][1] = __builtin_amdgcn_mfma_f32_16x16x32_bf16(wk0, xa[1][ks], kacc[0][1], 0, 0, 0);
            kacc[1][0] = __builtin_amdgcn_mfma_f32_16x16x32_bf16(wk1, xa[0][ks], kacc[1][0], 0, 0, 0);
            kacc[1][1] = __builtin_amdgcn_mfma_f32_16x16x32_bf16(wk1, xa[1][ks], kacc[1][1], 0, 0, 0);
            vacc[0][0] = __builtin_amdgcn_mfma_f32_16x16x32_bf16(xa[0][ks], wv0, vacc[0][0], 0, 0, 0);
            vacc[1][0] = __builtin_amdgcn_mfma_f32_16x16x32_bf16(xa[1][ks], wv0, vacc[1][0], 0, 0, 0);
            vacc[0][1] = __builtin_amdgcn_mfma_f32_16x16x32_bf16(xa[0][ks], wv1, vacc[0][1], 0, 0, 0);
            vacc[1][1] = __builtin_amdgcn_mfma_f32_16x16x32_bf16(xa[1][ks], wv1, vacc[1][1], 0, 0, 0);
            qacc[0] = __builtin_amdgcn_mfma_f32_16x16x32_bf16(xq[ks], wfrag(Wqp, 2 * h, ks), qacc[0], 0, 0, 0);
            qacc[1] = __builtin_amdgcn_mfma_f32_16x16x32_bf16(xq[ks], wfrag(Wqp, 2 * h + 1, ks), qacc[1], 0, 0, 0);
        }
    };

    auto produce_write = [&](int h) {
#pragma unroll
        for (int dm = 0; dm < 2; ++dm) {
            const f32x4 bkv = *(const f32x4*)(bk + h * 32 + dm * 16 + 4 * g);
            const int pos = ((dm * 2 + (g >> 1)) ^ kswz) << 3;
            const int sub = (4 * g) & 7;
#pragma unroll
            for (int tj = 0; tj < 2; ++tj) {
                bf16x4 kv;
#pragma unroll
                for (int r = 0; r < 4; ++r) kv[r] = (__bf16)(kacc[dm][tj][r] + bkv[r]);
                const int key = tk0 + tj * 16 + lo;
                *(bf16x4*)&sm.Kls[key * 32 + pos + sub] = kv;
            }
        }
#pragma unroll
        for (int nj = 0; nj < 2; ++nj) {
            const float bvv = bv[h * 32 + nj * 16 + lo];
#pragma unroll
            for (int mi = 0; mi < 2; ++mi) {
                bf16x4 vv4;
#pragma unroll
                for (int r = 0; r < 4; ++r) vv4[r] = (__bf16)(vacc[mi][nj][r] + bvv);
                *(bf16x4*)&sm.Vt[nj * 16 + lo][tk0 + mi * 16 + 4 * g] = vv4;
            }
        }
#pragma unroll
        for (int nj = 0; nj < 2; ++nj) {
            const float bqv = bq[h * 32 + nj * 16 + lo];
#pragma unroll
            for (int r = 0; r < 4; ++r)
                sm.Qs[w][(4 * g + r) * 32 + nj * 16 + lo] = (__bf16)(qacc[nj][r] + bqv);
        }
    };

    produce_compute(0);
    produce_write(0);
    __syncthreads();

#pragma unroll
    for (int h = 0; h < 4; ++h) {
        const bf16x8 qf = *(const bf16x8*)&sm.Qs[w][lo * 32 + g * 8];
        f32x4 s[16];
        __builtin_amdgcn_s_setprio(1);
#pragma unroll
        for (int f = 0; f < 16; ++f) {
            const bf16x8 kf =
                *(const bf16x8*)&sm.Kls[(f * 16 + lo) * 32 + ((g ^ kswz) << 3)];
            s[f] = __builtin_amdgcn_mfma_f32_16x16x32_bf16(
                kf, qf, f32x4{0.f, 0.f, 0.f, 0.f}, 0, 0, 0);
        }
        __builtin_amdgcn_s_setprio(0);

        float ls = 0.f;
#pragma unroll
        for (int f = 0; f < 16; ++f) {
            const f32x4 mk = *(const f32x4*)&sm.mb[f * 16 + g * 4];
#pragma unroll
            for (int r = 0; r < 4; ++r) {
                const float p = __builtin_amdgcn_exp2f(
                    s[f][r] * (kScale * kLog2e) + mk[r]);
                s[f][r] = p;
                ls += p;
            }
        }
        ls += __shfl_xor(ls, 16, 64);
        ls += __shfl_xor(ls, 32, 64);

        if constexpr (WEIGHTS) {
            if (strip == 1 && w == 7 && lo == 15) {
                const float inv = 1.f / ls;
                float* wrow = wout + ((size_t)b * 4 + h) * 256;
#pragma unroll
                for (int f = 0; f < 16; ++f)
#pragma unroll
                    for (int r = 0; r < 4; ++r)
                        wrow[f * 16 + g * 4 + r] = s[f][r] * inv;
            }
        }

        // PV in four quarter-P passes; s dead afterwards
        f32x4 o[2] = {f32x4{0.f, 0.f, 0.f, 0.f}, f32x4{0.f, 0.f, 0.f, 0.f}};
#pragma unroll
        for (int qt = 0; qt < 4; ++qt) {
#pragma unroll
            for (int fl = 0; fl < 4; ++fl) {
                const int ff = qt * 4 + fl;
#pragma unroll
                for (int pr = 0; pr < 2; ++pr) {
                    bf16x2 pk;
                    pk[0] = (__bf16)s[ff][2 * pr];
                    pk[1] = (__bf16)s[ff][2 * pr + 1];
                    const int e = fl * 16 + 4 * g + 2 * pr;
                    const int addr =
                        lo * 64 + ((((e >> 3) ^ (lo & 7)) << 3) | (e & 7));
                    *(bf16x2*)&sm.Pl[w][addr] = pk;
                }
            }
            __builtin_amdgcn_s_setprio(1);
#pragma unroll
            for (int ksl = 0; ksl < 2; ++ksl) {
                const int cc = ksl * 4 + g;
                const bf16x8 pa =
                    *(const bf16x8*)&sm.Pl[w][lo * 64 + ((cc ^ (lo & 7)) << 3)];
#pragma unroll
                for (int nf = 0; nf < 2; ++nf) {
                    const bf16x8 bvv =
                        *(const bf16x8*)&sm.Vt[nf * 16 + lo][(qt * 2 + ksl) * 32 + g * 8];
                    o[nf] = __builtin_amdgcn_mfma_f32_16x16x32_bf16(pa, bvv, o[nf], 0, 0, 0);
                }
            }
            __builtin_amdgcn_s_setprio(0);
        }

        if (h < 3) produce_compute(h + 1);  // pipelined (pre-barrier)

#pragma unroll
        for (int r = 0; r < 4; ++r) {
            const float inv = 1.f / __shfl(ls, 4 * g + r, 64);
            const int crow = w * 16 + g * 4 + r;
#pragma unroll
            for (int nf = 0; nf < 2; ++nf) {
                const int col = h * 32 + nf * 16 + lo;
                const int chunk = (col >> 3) ^ (crow & 7);
                sm.Ctx[crow * 128 + (chunk << 3) + (col & 7)] = (__bf16)(o[nf][r] * inv);
            }
        }
        if (h < 3) {
            __syncthreads();
            produce_write(h + 1);
            __syncthreads();
        }
    }

    // ---- O-projection + residual + LN1 (+ LEAF2 LN2 for strip 1) ----
    const size_t m0 = (size_t)b * 256 + strip * 128;
    f32x4 acc[8];
#pragma unroll
    for (int ni = 0; ni < 8; ++ni) acc[ni] = f32x4{0.f, 0.f, 0.f, 0.f};

    const int arow = w * 16 + lo;
#pragma unroll
    for (int ks = 0; ks < 4; ++ks) {
        const bf16x8 av =
            *(const bf16x8*)&sm.Ctx[arow * 128 + (((g + 4 * ks) ^ (arow & 7)) << 3)];
#pragma unroll
        for (int ni = 0; ni < 8; ++ni)
            acc[ni] = __builtin_amdgcn_mfma_f32_16x16x32_bf16(
                av, wfrag(Wop, ni, ks), acc[ni], 0, 0, 0);
    }

    float bcol[8], ga[8], be[8], g2a[8], b2a[8];
#pragma unroll
    for (int ni = 0; ni < 8; ++ni) {
        bcol[ni] = bo[ni * 16 + lo];
        ga[ni] = g1[ni * 16 + lo];
        be[ni] = b1[ni * 16 + lo];
    }
    if (LEAF2 && strip == 1) {
#pragma unroll
        for (int ni = 0; ni < 8; ++ni) {
            g2a[ni] = g2[ni * 16 + lo];
            b2a[ni] = b2[ni * 16 + lo];
        }
    }

    float vv[4][8];
    float s[4] = {0, 0, 0, 0}, s2[4] = {0, 0, 0, 0};
#pragma unroll
    for (int r = 0; r < 4; ++r) {
        const int local = strip * 128 + w * 16 + g * 4 + r;
#pragma unroll
        for (int ni = 0; ni < 8; ++ni) {
            const int col = ni * 16 + lo;
            const int chunk = (col >> 3) ^ (local & 7);
            const float rv = (float)sm.Xs[local * 128 + (chunk << 3) + (col & 7)];
            const float x = acc[ni][r] + bcol[ni] + rv;
            vv[r][ni] = x; s[r] += x; s2[r] += x * x;
        }
    }
#pragma unroll
    for (int r = 0; r < 4; ++r)
#pragma unroll
        for (int o = 1; o < 16; o <<= 1) {
            s[r] += __shfl_xor(s[r], o, 64);
            s2[r] += __shfl_xor(s2[r], o, 64);
        }
#pragma unroll
    for (int r = 0; r < 4; ++r) {
        const float mu = s[r] * (1.f / 128.f);
        const float var = s2[r] * (1.f / 128.f) - mu * mu;
        const float rs = rsqrtf(var + kEps);
        const size_t mm = m0 + w * 16 + g * 4 + r;
        float yv[8];
        float ys = 0.f, ys2 = 0.f;
#pragma unroll
        for (int ni = 0; ni < 8; ++ni) {
            const __bf16 ov = (__bf16)(ga[ni] * (vv[r][ni] - mu) * rs + be[ni]);
            O1[mm * 128 + ni * 16 + lo] = ov;
            if (LEAF2 && strip == 1) {
                const float y = 2.f * (float)ov;   // leaf rows: y = 2*o1
                yv[ni] = y; ys += y; ys2 += y * y;
            }
        }
        if (LEAF2 && strip == 1) {
#pragma unroll
            for (int o = 1; o < 16; o <<= 1) {
                ys += __shfl_xor(ys, o, 64);
                ys2 += __shfl_xor(ys2, o, 64);
            }
            const float mu2 = ys * (1.f / 128.f);
            const float var2 = ys2 * (1.f / 128.f) - mu2 * mu2;
            const float rs2 = rsqrtf(var2 + kEps);
#pragma unroll
            for (int ni = 0; ni < 8; ++ni) {
                const float val = g2a[ni] * (yv[ni] - mu2) * rs2 + b2a[ni];
                const int col = ni * 16 + lo;
                if constexpr (LEAF2 == 1) {
                    const int chunk = (col >> 3) ^ ((int)mm & 7);
                    xb2[mm * 128 + chunk * 8 + (col & 7)] = (__bf16)val;
                } else if constexpr (LEAF2 == 2) {
                    xo2[mm * 128 + col] = val;
                }
            }
        }
    }
}

// ---------------------------------------------------------------------------
// Tree phase (strip-0 blocks only): level 6 from global O1, levels 5..0 in
// e[127][128] f32 (aliases Xs), LN2 rows 0..127. 512 threads / 8 waves.
// ---------------------------------------------------------------------------
__device__ void tree_phase0(
    SMem& sm, const __bf16* O1, const float* gamma, const float* beta,
    float* xo, __bf16* xb, int wf32, int wbf16, int b)
{
    float* e = (float*)sm.Xs;   // [127][128] = 63.5KB
    const int t = threadIdx.x;
    const int wv = t >> 6, lane = t & 63;
    const __bf16* ob = O1 + (size_t)b * 32768;
    const float2 gv = *(const float2*)(gamma + lane * 2);
    const float2 bb = *(const float2*)(beta + lane * 2);
    const int c = lane * 2;

    // level 6 from global: parents 63..126 (children 127..254)
#pragma unroll
    for (int it = 0; it < 2; ++it) {
        const int q = it * 512 + t;
        const int p = 63 + (q >> 4);
        const int cg = (q & 15) * 8;
        const bf16x8 c1 = *(const bf16x8*)(ob + (size_t)(2 * p + 1) * 128 + cg);
        const bf16x8 c2 = *(const bf16x8*)(ob + (size_t)(2 * p + 2) * 128 + cg);
        f32x4 r0, r1;
#pragma unroll
        for (int i = 0; i < 4; ++i) r0[i] = tanhf((float)c1[i] + (float)c2[i]);
#pragma unroll
        for (int i = 0; i < 4; ++i) r1[i] = tanhf((float)c1[4 + i] + (float)c2[4 + i]);
        *(f32x4*)&e[p * 128 + cg] = r0;
        *(f32x4*)&e[p * 128 + cg + 4] = r1;
    }
    __syncthreads();

    // levels 5..0: wave wv owns cols wv*16..wv*16+15, barrier-free
    {
        const int col = wv * 16 + (lane & 15);
        const int nsub = lane >> 4;
        for (int lvl = 5; lvl >= 0; --lvl) {
            const int p0 = (1 << lvl) - 1;
            const int cntn = 1 << lvl;
            for (int base = 0; base < cntn; base += 4) {
                const int p = p0 + base + nsub;
                if (base + nsub < cntn)
                    e[p * 128 + col] =
                        tanhf(e[(2 * p + 1) * 128 + col] + e[(2 * p + 2) * 128 + col]);
            }
        }
    }
    __syncthreads();

    // LN2 rows 0..127 (row 127 is a leaf)
    for (int row = wv; row < 128; row += 8) {
        const bf16x2 v = *(const bf16x2*)(ob + (size_t)row * 128 + c);
        float y0, y1;
        if (row < 127) {
            y0 = (float)v[0] + e[row * 128 + c];
            y1 = (float)v[1] + e[row * 128 + c + 1];
        } else {
            y0 = 2.f * (float)v[0];
            y1 = 2.f * (float)v[1];
        }
        float s = y0 + y1, s2 = y0 * y0 + y1 * y1;
#pragma unroll
        for (int o = 1; o < 64; o <<= 1) {
            s += __shfl_xor(s, o, 64);
            s2 += __shfl_xor(s2, o, 64);
        }
        const float mu = s * (1.f / 128.f);
        const float var = s2 * (1.f / 128.f) - mu * mu;
        const float rs = rsqrtf(var + kEps);
        const float r0 = gv.x * (y0 - mu) * rs + bb.x;
        const float r1 = gv.y * (y1 - mu) * rs + bb.y;
        const size_t rowoff = ((size_t)b * 256 + row) * 128;
        if (wf32) {
            float2 o2; o2.x = r0; o2.y = r1;
            *(float2*)(xo + rowoff + c) = o2;
        }
        if (wbf16) {
            const int chunk = (c >> 3) ^ (row & 7);
            bf16x2 ob2; ob2[0] = (__bf16)r0; ob2[1] = (__bf16)r1;
            *(bf16x2*)(xb + rowoff + chunk * 8 + (c & 7)) = ob2;
        }
    }
}

// ---------------------------------------------------------------------------
// ONE kernel: wtrans-share -> [bar] -> mega L0 -> [bar] -> tree L0 -> [bar]
// -> mega L1 -> [bar] -> tree L1. 256 blocks x 512 threads, 1 block/CU.
// ---------------------------------------------------------------------------
__global__ __launch_bounds__(512) void fused_net(
    const float* __restrict__ x_in, const float* __restrict__ mask,
    const float* __restrict__ Wq, const float* __restrict__ Wk,
    const float* __restrict__ Wv, const float* __restrict__ Wo,
    const float* __restrict__ bq, const float* __restrict__ bk,
    const float* __restrict__ bv, const float* __restrict__ bo,
    const float* __restrict__ g1, const float* __restrict__ b1,
    const float* __restrict__ g2, const float* __restrict__ b2,
    __bf16* Wt, __bf16* O1, __bf16* xb,
    float* out_x, float* out_w, float* out_l1, int* cnt)
{
    __shared__ SMem sm;
    const int t = threadIdx.x;
    const int b = blockIdx.x & 127;
    const int strip = blockIdx.x >> 7;

    // ---- prologue: stage Xs (layer-0 f32) + wtrans share + mask bias ----
#pragma unroll
    for (int p = 0; p < 8; ++p) {
        const int ci = p * 512 + t;
        const int row = ci >> 4, cc = ci & 15;
        const float* src = x_in + ((size_t)b * 256 + row) * 128 + cc * 8;
        const float4 a0 = *(const float4*)src;
        const float4 a1 = *(const float4*)(src + 4);
        bf16x8 o;
        o[0] = (__bf16)a0.x; o[1] = (__bf16)a0.y; o[2] = (__bf16)a0.z; o[3] = (__bf16)a0.w;
        o[4] = (__bf16)a1.x; o[5] = (__bf16)a1.y; o[6] = (__bf16)a1.z; o[7] = (__bf16)a1.w;
        *(bf16x8*)&sm.Xs[row * 128 + ((cc ^ (row & 7)) << 3)] = o;
    }
    {   // weight transpose to fragment-major: exactly 1 element per thread
        const int idx = blockIdx.x * 512 + t;       // 0..131071
        const int m = idx >> 14;                    // l*4 + mtx
        const int rest = idx & 16383;
        const int k = rest >> 7, n = rest & 127;
        const float* srcs[4] = {Wq, Wk, Wv, Wo};
        const float v = srcs[m & 3][(size_t)(m >> 2) * 16384 + rest];
        const int lo2 = n & 15, ni = n >> 4;
        const int j = k & 7, tt = k >> 3, gg = tt & 3, ks = tt >> 2;
        Wt[(size_t)m * 16384 + ((ni * 4 + ks) * 64 + gg * 16 + lo2) * 8 + j] = (__bf16)v;
    }
    if (t < 256) sm.mb[t] = mask[b * 256 + t] * (kNeg * kLog2e);

    gridbar(cnt + 0, 256);   // Wt ready everywhere

    // ---- layer 0 ----
    mega_phase<0, false, 1>(sm, nullptr, Wt, bq, bk, bv, bo, g1, b1, g2, b2,
                            O1, nullptr, nullptr, nullptr, xb);
    gridbar(cnt + 1, 256);   // O1 (L0) ready

    if (strip == 0)
        tree_phase0(sm, O1, g2, b2, nullptr, xb, 0, 1, b);
    gridbar(cnt + 2, 256);   // xb ready

    // ---- layer 1 ----
    mega_phase<1, true, 2>(sm, xb, Wt + 4 * 16384,
                           bq + kD, bk + kD, bv + kD, bo + kD,
                           g1 + kD, b1 + kD, g2 + kD, b2 + kD,
                           O1, out_w, out_l1, out_x, nullptr);
    gridbar(cnt + 3, 256);   // O1 (L1) ready

    if (strip == 0)
        tree_phase0(sm, O1, g2 + kD, b2 + kD, out_x, nullptr, 1, 0, b);
}

// ---------------------------------------------------------------------------
extern "C" void kernel_launch(void* const* d_in, const int* in_sizes, int n_in,
                              void* d_out, int out_size, void* d_ws, size_t ws_size,
                              hipStream_t stream)
{
    (void)in_sizes; (void)n_in; (void)out_size; (void)ws_size;

    const float* x_in = (const float*)d_in[0];
    const float* mask = (const float*)d_in[1];
    const float* Wq = (const float*)d_in[5];
    const float* bq = (const float*)d_in[6];
    const float* Wk = (const float*)d_in[7];
    const float* bk = (const float*)d_in[8];
    const float* Wv = (const float*)d_in[9];
    const float* bv = (const float*)d_in[10];
    const float* Wo = (const float*)d_in[11];
    const float* bo = (const float*)d_in[12];
    const float* g1 = (const float*)d_in[13];
    const float* b1 = (const float*)d_in[14];
    const float* g2 = (const float*)d_in[15];
    const float* b2 = (const float*)d_in[16];

    float* out_x = (float*)d_out;
    float* out_l1 = out_x + kSZ;
    float* out_w = out_l1 + 1;

    char* wsb = (char*)d_ws;
    __bf16* O1 = (__bf16*)wsb;                       // 8MB
    __bf16* xb = (__bf16*)(wsb + kSZ * 2);           // 8MB, pre-swizzled
    __bf16* Wt = (__bf16*)(wsb + 2 * kSZ * 2);       // 256KB, frag-major
    int* cnt = (int*)(wsb + 2 * kSZ * 2 + 8 * 16384 * 2);  // 4 barrier counters

    hipMemsetAsync(cnt, 0, 4 * sizeof(int), stream);
    fused_net<<<256, 512, 0, stream>>>(x_in, mask, Wq, Wk, Wv, Wo,
                                       bq, bk, bv, bo, g1, b1, g2, b2,
                                       Wt, O1, xb, out_x, out_w, out_l1, cnt);
}

// Round 19
// 94.784 us; speedup vs baseline: 2.8838x; 2.8838x over previous
//
#include <hip/hip_runtime.h>
#include <math.h>

typedef __bf16 bf16x8 __attribute__((ext_vector_type(8)));
typedef __bf16 bf16x4 __attribute__((ext_vector_type(4)));
typedef __bf16 bf16x2 __attribute__((ext_vector_type(2)));
typedef float f32x4 __attribute__((ext_vector_type(4)));

namespace {
constexpr int kB = 128, kS = 256, kD = 128, kH = 4;
constexpr float kEps = 1e-6f;
constexpr float kScale = 0.17677669529663687f;  // 1/sqrt(32)
constexpr float kNeg = -1000000000.0f;
constexpr float kLog2e = 1.4426950408889634f;
constexpr size_t kSZ = (size_t)kB * kS * kD;    // 4,194,304
}

// ---------------------------------------------------------------------------
// global->LDS async DMA, 16 B/lane.
// ---------------------------------------------------------------------------
__device__ __forceinline__ void glds16(const void* g, void* l) {
    __builtin_amdgcn_global_load_lds(
        (const __attribute__((address_space(1))) unsigned int*)g,
        (__attribute__((address_space(3))) unsigned int*)l, 16, 0, 0);
}

// ---------------------------------------------------------------------------
// Weight transpose + convert + FRAGMENT-MAJOR packing:
// frag(ni,ks)[lane l][j] = W^T[ni*16 + (l&15)][((l>>4) + 4*ks)*8 + j]
// ---------------------------------------------------------------------------
__global__ __launch_bounds__(256) void wtrans(
    const float* __restrict__ Wq, const float* __restrict__ Wk,
    const float* __restrict__ Wv, const float* __restrict__ Wo,
    __bf16* __restrict__ Wt)
{
    const int mtx = blockIdx.x & 3, l = blockIdx.x >> 2;
    const float* W = (mtx == 0 ? Wq : mtx == 1 ? Wk : mtx == 2 ? Wv : Wo) +
                     (size_t)l * kD * kD;
    __bf16* o = Wt + (size_t)blockIdx.x * kD * kD;
    for (int idx = threadIdx.x; idx < kD * kD; idx += 256) {
        const int k = idx >> 7, n = idx & 127;
        const int lo = n & 15, ni = n >> 4;
        const int j = k & 7, tt = k >> 3, g = tt & 3, ks = tt >> 2;
        o[((ni * 4 + ks) * 64 + g * 16 + lo) * 8 + j] = (__bf16)W[idx];
    }
}

// ---------------------------------------------------------------------------
// MEGA-KERNEL (round-17 known-good structure) + Qs STRIDE-40 FIX:
// Qs was an 8-way LDS bank conflict on both its b128 read (64*lo mod 128
// cycles 2 values) and scalar writes; stride 40 bf16 (80B = 20 banks, odd*4)
// makes both sides 2-way (free per m136). Evidence: r18's fused dispatch
// exposed SQ_LDS_BANK_CONFLICT = 1.66e7 in this code path.
// ---------------------------------------------------------------------------
template <int WEIGHTS, bool F32X>
__global__ __launch_bounds__(512) void mega_attn(
    const void* __restrict__ xsrc, const __bf16* __restrict__ Wp,
    const float* __restrict__ bq, const float* __restrict__ bk,
    const float* __restrict__ bv, const float* __restrict__ bo,
    const float* __restrict__ mask, const float* __restrict__ gamma,
    const float* __restrict__ beta, __bf16* __restrict__ O1,
    float* __restrict__ wout, float* __restrict__ l1out)
{
    __shared__ __bf16 Xs[256 * 128];   // 64KB swizzled x (also the residual)
    __shared__ __bf16 Kls[256 * 32];   // 16KB, XOR-swizzled chunks
    __shared__ __bf16 Vt[32][276];     // 17.25KB V^T
    __shared__ __bf16 Pl[8][16 * 64];  // 16KB per-wave quarter-P
    __shared__ __bf16 Qs[8][16 * 40];  // 10KB per-wave Q_h, stride 40 (no 8-way)
    __shared__ __bf16 Ctx[128 * 128];  // 32KB swizzled ctx
    __shared__ float mb[256];

    const int t = threadIdx.x;
    const int w = t >> 6, l = t & 63, lo = l & 15, g = l >> 4;
    const int b = blockIdx.x & 127, strip = blockIdx.x >> 7;
    const int q0 = strip * 128 + w * 16;
    const int tk0 = w * 32;
    const int kswz = (lo ^ (lo >> 2)) & 3;

    const __bf16* Wqp = Wp;
    const __bf16* Wkp = Wp + 16384;
    const __bf16* Wvp = Wp + 2 * 16384;
    const __bf16* Wop = Wp + 3 * 16384;

    // ---- stage Xs (full batch, swizzled) ----
    if constexpr (F32X) {
#pragma unroll
        for (int p = 0; p < 8; ++p) {
            const int ci = p * 512 + t;
            const int row = ci >> 4, c = ci & 15;
            const float* src = (const float*)xsrc +
                               ((size_t)b * 256 + row) * 128 + c * 8;
            const float4 a0 = *(const float4*)src;
            const float4 a1 = *(const float4*)(src + 4);
            bf16x8 o;
            o[0] = (__bf16)a0.x; o[1] = (__bf16)a0.y; o[2] = (__bf16)a0.z; o[3] = (__bf16)a0.w;
            o[4] = (__bf16)a1.x; o[5] = (__bf16)a1.y; o[6] = (__bf16)a1.z; o[7] = (__bf16)a1.w;
            *(bf16x8*)&Xs[row * 128 + ((c ^ (row & 7)) << 3)] = o;
        }
    } else {
#pragma unroll
        for (int it = 0; it < 8; ++it)
            glds16((const __bf16*)xsrc + (size_t)b * 32768 + (it * 8 + w) * 512 + l * 8,
                   &Xs[(it * 8 + w) * 512]);
    }
    if (t < 256) mb[t] = mask[b * 256 + t] * (kNeg * kLog2e);
    if (WEIGHTS && blockIdx.x == 0 && t == 0) l1out[0] = 1024.0f;
    __syncthreads();

    auto wfrag = [&](const __bf16* W, int ni, int ks) {
        return *(const bf16x8*)(W + (((ni * 4 + ks) * 64 + l) << 3));
    };
    auto xfrag = [&](int row, int ks) {
        return *(const bf16x8*)&Xs[row * 128 + (((g + 4 * ks) ^ (row & 7)) << 3)];
    };

    // head-invariant X fragments (hoisted)
    bf16x8 xa[2][4], xq[4];
#pragma unroll
    for (int ks = 0; ks < 4; ++ks) {
        xa[0][ks] = xfrag(tk0 + lo, ks);
        xa[1][ks] = xfrag(tk0 + 16 + lo, ks);
        xq[ks] = xfrag(q0 + lo, ks);
    }

    f32x4 kacc[2][2], vacc[2][2], qacc[2];

    auto produce_compute = [&](int h) {
#pragma unroll
        for (int i = 0; i < 2; ++i)
#pragma unroll
            for (int j2 = 0; j2 < 2; ++j2) {
                kacc[i][j2] = f32x4{0.f, 0.f, 0.f, 0.f};
                vacc[i][j2] = f32x4{0.f, 0.f, 0.f, 0.f};
            }
        qacc[0] = f32x4{0.f, 0.f, 0.f, 0.f};
        qacc[1] = f32x4{0.f, 0.f, 0.f, 0.f};
#pragma unroll
        for (int ks = 0; ks < 4; ++ks) {
            const bf16x8 wk0 = wfrag(Wkp, 2 * h, ks);
            const bf16x8 wk1 = wfrag(Wkp, 2 * h + 1, ks);
            const bf16x8 wv0 = wfrag(Wvp, 2 * h, ks);
            const bf16x8 wv1 = wfrag(Wvp, 2 * h + 1, ks);
            kacc[0][0] = __builtin_amdgcn_mfma_f32_16x16x32_bf16(wk0, xa[0][ks], kacc[0][0], 0, 0, 0);
            kacc[0][1] = __builtin_amdgcn_mfma_f32_16x16x32_bf16(wk0, xa[1][ks], kacc[0][1], 0, 0, 0);
            kacc[1][0] = __builtin_amdgcn_mfma_f32_16x16x32_bf16(wk1, xa[0][ks], kacc[1][0], 0, 0, 0);
            kacc[1][1] = __builtin_amdgcn_mfma_f32_16x16x32_bf16(wk1, xa[1][ks], kacc[1][1], 0, 0, 0);
            vacc[0][0] = __builtin_amdgcn_mfma_f32_16x16x32_bf16(xa[0][ks], wv0, vacc[0][0], 0, 0, 0);
            vacc[1][0] = __builtin_amdgcn_mfma_f32_16x16x32_bf16(xa[1][ks], wv0, vacc[1][0], 0, 0, 0);
            vacc[0][1] = __builtin_amdgcn_mfma_f32_16x16x32_bf16(xa[0][ks], wv1, vacc[0][1], 0, 0, 0);
            vacc[1][1] = __builtin_amdgcn_mfma_f32_16x16x32_bf16(xa[1][ks], wv1, vacc[1][1], 0, 0, 0);
            qacc[0] = __builtin_amdgcn_mfma_f32_16x16x32_bf16(xq[ks], wfrag(Wqp, 2 * h, ks), qacc[0], 0, 0, 0);
            qacc[1] = __builtin_amdgcn_mfma_f32_16x16x32_bf16(xq[ks], wfrag(Wqp, 2 * h + 1, ks), qacc[1], 0, 0, 0);
        }
    };

    auto produce_write = [&](int h) {
#pragma unroll
        for (int dm = 0; dm < 2; ++dm) {
            const f32x4 bkv = *(const f32x4*)(bk + h * 32 + dm * 16 + 4 * g);
            const int pos = ((dm * 2 + (g >> 1)) ^ kswz) << 3;
            const int sub = (4 * g) & 7;
#pragma unroll
            for (int tj = 0; tj < 2; ++tj) {
                bf16x4 kv;
#pragma unroll
                for (int r = 0; r < 4; ++r) kv[r] = (__bf16)(kacc[dm][tj][r] + bkv[r]);
                const int key = tk0 + tj * 16 + lo;
                *(bf16x4*)&Kls[key * 32 + pos + sub] = kv;
            }
        }
#pragma unroll
        for (int nj = 0; nj < 2; ++nj) {
            const float bvv = bv[h * 32 + nj * 16 + lo];
#pragma unroll
            for (int mi = 0; mi < 2; ++mi) {
                bf16x4 vv4;
#pragma unroll
                for (int r = 0; r < 4; ++r) vv4[r] = (__bf16)(vacc[mi][nj][r] + bvv);
                *(bf16x4*)&Vt[nj * 16 + lo][tk0 + mi * 16 + 4 * g] = vv4;
            }
        }
#pragma unroll
        for (int nj = 0; nj < 2; ++nj) {
            const float bqv = bq[h * 32 + nj * 16 + lo];
#pragma unroll
            for (int r = 0; r < 4; ++r)
                Qs[w][(4 * g + r) * 40 + nj * 16 + lo] = (__bf16)(qacc[nj][r] + bqv);
        }
    };

    // prologue: head 0
    produce_compute(0);
    produce_write(0);
    __syncthreads();

#pragma unroll
    for (int h = 0; h < 4; ++h) {
        // ======== CONSUME: QK^T -> softmax -> PV ========
        const bf16x8 qf = *(const bf16x8*)&Qs[w][lo * 40 + g * 8];
        f32x4 s[16];
        __builtin_amdgcn_s_setprio(1);
#pragma unroll
        for (int f = 0; f < 16; ++f) {
            const bf16x8 kf =
                *(const bf16x8*)&Kls[(f * 16 + lo) * 32 + ((g ^ kswz) << 3)];
            s[f] = __builtin_amdgcn_mfma_f32_16x16x32_bf16(
                kf, qf, f32x4{0.f, 0.f, 0.f, 0.f}, 0, 0, 0);
        }
        __builtin_amdgcn_s_setprio(0);

        float ls = 0.f;
#pragma unroll
        for (int f = 0; f < 16; ++f) {
            const f32x4 mk = *(const f32x4*)&mb[f * 16 + g * 4];
#pragma unroll
            for (int r = 0; r < 4; ++r) {
                const float p = __builtin_amdgcn_exp2f(
                    s[f][r] * (kScale * kLog2e) + mk[r]);
                s[f][r] = p;
                ls += p;
            }
        }
        ls += __shfl_xor(ls, 16, 64);
        ls += __shfl_xor(ls, 32, 64);

        if constexpr (WEIGHTS) {
            if (strip == 1 && w == 7 && lo == 15) {
                const float inv = 1.f / ls;
                float* wrow = wout + ((size_t)b * 4 + h) * 256;
#pragma unroll
                for (int f = 0; f < 16; ++f)
#pragma unroll
                    for (int r = 0; r < 4; ++r)
                        wrow[f * 16 + g * 4 + r] = s[f][r] * inv;
            }
        }

        // PV in four quarter-P passes (64 keys each); s dead afterwards
        f32x4 o[2] = {f32x4{0.f, 0.f, 0.f, 0.f}, f32x4{0.f, 0.f, 0.f, 0.f}};
#pragma unroll
        for (int qt = 0; qt < 4; ++qt) {
#pragma unroll
            for (int fl = 0; fl < 4; ++fl) {
                const int ff = qt * 4 + fl;
#pragma unroll
                for (int pr = 0; pr < 2; ++pr) {
                    bf16x2 pk;
                    pk[0] = (__bf16)s[ff][2 * pr];
                    pk[1] = (__bf16)s[ff][2 * pr + 1];
                    const int e = fl * 16 + 4 * g + 2 * pr;
                    const int addr =
                        lo * 64 + ((((e >> 3) ^ (lo & 7)) << 3) | (e & 7));
                    *(bf16x2*)&Pl[w][addr] = pk;
                }
            }
            __builtin_amdgcn_s_setprio(1);
#pragma unroll
            for (int ksl = 0; ksl < 2; ++ksl) {
                const int cc = ksl * 4 + g;
                const bf16x8 pa =
                    *(const bf16x8*)&Pl[w][lo * 64 + ((cc ^ (lo & 7)) << 3)];
#pragma unroll
                for (int nf = 0; nf < 2; ++nf) {
                    const bf16x8 bvv =
                        *(const bf16x8*)&Vt[nf * 16 + lo][(qt * 2 + ksl) * 32 + g * 8];
                    o[nf] = __builtin_amdgcn_mfma_f32_16x16x32_bf16(pa, bvv, o[nf], 0, 0, 0);
                }
            }
            __builtin_amdgcn_s_setprio(0);
        }

        // ---- pipelined produce-compute for next head (pre-barrier) ----
        if (h < 3) produce_compute(h + 1);

        // normalized ctx -> swizzled LDS tile (cols h*32..h*32+31)
#pragma unroll
        for (int r = 0; r < 4; ++r) {
            const float inv = 1.f / __shfl(ls, 4 * g + r, 64);
            const int crow = w * 16 + g * 4 + r;
#pragma unroll
            for (int nf = 0; nf < 2; ++nf) {
                const int col = h * 32 + nf * 16 + lo;
                const int chunk = (col >> 3) ^ (crow & 7);
                Ctx[crow * 128 + (chunk << 3) + (col & 7)] = (__bf16)(o[nf][r] * inv);
            }
        }
        if (h < 3) {
            __syncthreads();          // all Kls/Vt reads of head h complete
            produce_write(h + 1);     // only the write stage is serialized
            __syncthreads();
        }
    }

    // ======== O-projection + residual + LN1 ========
    const size_t m0 = (size_t)b * 256 + strip * 128;
    f32x4 acc[8];
#pragma unroll
    for (int ni = 0; ni < 8; ++ni) acc[ni] = f32x4{0.f, 0.f, 0.f, 0.f};

    const int arow = w * 16 + lo;
#pragma unroll
    for (int ks = 0; ks < 4; ++ks) {
        const bf16x8 av =
            *(const bf16x8*)&Ctx[arow * 128 + (((g + 4 * ks) ^ (arow & 7)) << 3)];
#pragma unroll
        for (int ni = 0; ni < 8; ++ni)
            acc[ni] = __builtin_amdgcn_mfma_f32_16x16x32_bf16(
                av, wfrag(Wop, ni, ks), acc[ni], 0, 0, 0);
    }

    float bcol[8], ga[8], be[8];
#pragma unroll
    for (int ni = 0; ni < 8; ++ni) {
        bcol[ni] = bo[ni * 16 + lo];
        ga[ni] = gamma[ni * 16 + lo];
        be[ni] = beta[ni * 16 + lo];
    }

    float vv[4][8];
    float s[4] = {0, 0, 0, 0}, s2[4] = {0, 0, 0, 0};
#pragma unroll
    for (int r = 0; r < 4; ++r) {
        const int local = strip * 128 + w * 16 + g * 4 + r;
#pragma unroll
        for (int ni = 0; ni < 8; ++ni) {
            const int col = ni * 16 + lo;
            const int chunk = (col >> 3) ^ (local & 7);
            const float rv = (float)Xs[local * 128 + (chunk << 3) + (col & 7)];
            const float x = acc[ni][r] + bcol[ni] + rv;
            vv[r][ni] = x; s[r] += x; s2[r] += x * x;
        }
    }
#pragma unroll
    for (int r = 0; r < 4; ++r)
#pragma unroll
        for (int o = 1; o < 16; o <<= 1) {
            s[r] += __shfl_xor(s[r], o, 64);
            s2[r] += __shfl_xor(s2[r], o, 64);
        }
#pragma unroll
    for (int r = 0; r < 4; ++r) {
        const float mu = s[r] * (1.f / 128.f);
        const float var = s2[r] * (1.f / 128.f) - mu * mu;
        const float rs = rsqrtf(var + kEps);
        const size_t mm = m0 + w * 16 + g * 4 + r;
#pragma unroll
        for (int ni = 0; ni < 8; ++ni)
            O1[mm * 128 + ni * 16 + lo] =
                (__bf16)(ga[ni] * (vv[r][ni] - mu) * rs + be[ni]);
    }
}

// ---------------------------------------------------------------------------
// FUSED tree aggregation + residual + LayerNorm2 (round-15/16/17 known-good).
// ---------------------------------------------------------------------------
__global__ __launch_bounds__(1024) void tree_ln(
    const __bf16* __restrict__ o1, const float* __restrict__ gamma,
    const float* __restrict__ beta, float* __restrict__ xo,
    __bf16* __restrict__ xb, int wf32, int wbf16)
{
    __shared__ float e[127 * 132];   // internal nodes only
    const int isleaf = blockIdx.x >> 7;
    const int b = blockIdx.x & 127;
    const int t = threadIdx.x;
    const __bf16* ob = o1 + (size_t)b * 256 * 128;
    const int wv = t >> 6, lane = t & 63;
    const float2 gv = *(const float2*)(gamma + lane * 2);
    const float2 bb = *(const float2*)(beta + lane * 2);
    const int c = lane * 2;

    auto ln_store = [&](int row, float y0, float y1) {
        float s = y0 + y1, s2 = y0 * y0 + y1 * y1;
#pragma unroll
        for (int o = 1; o < 64; o <<= 1) {
            s += __shfl_xor(s, o, 64);
            s2 += __shfl_xor(s2, o, 64);
        }
        const float mu = s * (1.f / 128.f);
        const float var = s2 * (1.f / 128.f) - mu * mu;
        const float rs = rsqrtf(var + kEps);
        const float r0 = gv.x * (y0 - mu) * rs + bb.x;
        const float r1 = gv.y * (y1 - mu) * rs + bb.y;
        const size_t rowoff = ((size_t)b * 256 + row) * 128;
        if (wf32) {
            float2 o2; o2.x = r0; o2.y = r1;
            *(float2*)(xo + rowoff + c) = o2;
        }
        if (wbf16) {
            const int chunk = (c >> 3) ^ (row & 7);
            bf16x2 ob2; ob2[0] = (__bf16)r0; ob2[1] = (__bf16)r1;
            *(bf16x2*)(xb + rowoff + chunk * 8 + (c & 7)) = ob2;
        }
    };

    if (isleaf) {
        for (int row = 128 + wv; row < 256; row += 16) {
            const bf16x2 v = *(const bf16x2*)(ob + (size_t)row * 128 + c);
            ln_store(row, 2.f * (float)v[0], 2.f * (float)v[1]);
        }
        return;
    }

    // level 6 straight from global: parents 63..126, children 127..254
    {
        const int p = 63 + (t >> 4);
        const int cg = (t & 15) * 8;
        const bf16x8 c1 = *(const bf16x8*)(ob + (size_t)(2 * p + 1) * 128 + cg);
        const bf16x8 c2 = *(const bf16x8*)(ob + (size_t)(2 * p + 2) * 128 + cg);
        f32x4 r0, r1;
#pragma unroll
        for (int i = 0; i < 4; ++i)
            r0[i] = tanhf((float)c1[i] + (float)c2[i]);
#pragma unroll
        for (int i = 0; i < 4; ++i)
            r1[i] = tanhf((float)c1[4 + i] + (float)c2[4 + i]);
        *(f32x4*)&e[p * 132 + cg] = r0;
        *(f32x4*)&e[p * 132 + cg + 4] = r1;
    }
    __syncthreads();

    {
        const int col = wv * 8 + (lane & 7);
        const int nsub = lane >> 3;
        for (int lvl = 5; lvl >= 0; --lvl) {
            const int p0 = (1 << lvl) - 1;
            const int cnt = 1 << lvl;
            for (int base = 0; base < cnt; base += 8) {
                const int p = p0 + base + nsub;
                if (base + nsub < cnt) {
                    e[p * 132 + col] =
                        tanhf(e[(2 * p + 1) * 132 + col] + e[(2 * p + 2) * 132 + col]);
                }
            }
        }
    }
    __syncthreads();

    for (int row = wv; row < 128; row += 16) {
        const bf16x2 v = *(const bf16x2*)(ob + (size_t)row * 128 + c);
        float y0, y1;
        if (row < 127) {
            y0 = (float)v[0] + e[row * 132 + c];
            y1 = (float)v[1] + e[row * 132 + c + 1];
        } else {
            y0 = 2.f * (float)v[0];
            y1 = 2.f * (float)v[1];
        }
        ln_store(row, y0, y1);
    }
}

// ---------------------------------------------------------------------------
extern "C" void kernel_launch(void* const* d_in, const int* in_sizes, int n_in,
                              void* d_out, int out_size, void* d_ws, size_t ws_size,
                              hipStream_t stream)
{
    (void)in_sizes; (void)n_in; (void)out_size; (void)ws_size;

    const float* x_in = (const float*)d_in[0];
    const float* mask = (const float*)d_in[1];
    const float* Wq = (const float*)d_in[5];
    const float* bq = (const float*)d_in[6];
    const float* Wk = (const float*)d_in[7];
    const float* bk = (const float*)d_in[8];
    const float* Wv = (const float*)d_in[9];
    const float* bv = (const float*)d_in[10];
    const float* Wo = (const float*)d_in[11];
    const float* bo = (const float*)d_in[12];
    const float* g1 = (const float*)d_in[13];
    const float* b1 = (const float*)d_in[14];
    const float* g2 = (const float*)d_in[15];
    const float* b2 = (const float*)d_in[16];

    float* out_x = (float*)d_out;
    float* out_l1 = out_x + kSZ;
    float* out_w = out_l1 + 1;

    char* wsb = (char*)d_ws;
    __bf16* O1 = (__bf16*)wsb;                   // 8MB
    __bf16* xb = (__bf16*)(wsb + kSZ * 2);       // 8MB, pre-swizzled bf16 x
    __bf16* Wt = (__bf16*)(wsb + 2 * kSZ * 2);   // 8 * 16384 bf16, frag-major

    wtrans<<<8, 256, 0, stream>>>(Wq, Wk, Wv, Wo, Wt);

    // ---- layer 0 (f32 x_in) ----
    mega_attn<0, true><<<256, 512, 0, stream>>>(x_in, Wt, bq, bk, bv, bo,
                                                mask, g1, b1, O1,
                                                nullptr, nullptr);
    tree_ln<<<256, 1024, 0, stream>>>(O1, g2, b2, nullptr, xb, 0, 1);

    // ---- layer 1 (bf16 xb, pre-swizzled) ----
    mega_attn<1, false><<<256, 512, 0, stream>>>(xb, Wt + 4 * 16384,
                                                 bq + kD, bk + kD, bv + kD, bo + kD,
                                                 mask, g1 + kD, b1 + kD, O1,
                                                 out_w, out_l1);
    tree_ln<<<256, 1024, 0, stream>>>(O1, g2 + kD, b2 + kD, out_x, nullptr, 1, 0);
}